// Round 5
// baseline (1553.040 us; speedup 1.0000x reference)
//
#include <hip/hip_runtime.h>
#include <hip/hip_cooperative_groups.h>
#include <cmath>

namespace cg = cooperative_groups;

#define HIDC 48

// ---------------------------------------------------------------------------
// Reduce NV per-thread values across a 256-thread block (4 waves).
// Results land in red[0..NV-1]. red needs >= 4*NV floats.
// Leading __syncthreads protects red from the caller's previous use.
// ---------------------------------------------------------------------------
template <int NV>
__device__ __forceinline__ void block_reduce_vec(float* v, float* red)
{
    const int t = threadIdx.x;
#pragma unroll
    for (int off = 32; off > 0; off >>= 1)
#pragma unroll
        for (int j = 0; j < NV; ++j)
            v[j] += __shfl_down(v[j], off);
    __syncthreads();
    if ((t & 63) == 0)
#pragma unroll
        for (int j = 0; j < NV; ++j) red[(t >> 6) * NV + j] = v[j];
    __syncthreads();
    if (t < NV)
        red[t] = red[t] + red[NV + t] + red[2 * NV + t] + red[3 * NV + t];
    __syncthreads();
}

// ---------------------------------------------------------------------------
// conv3x3(48ch, SAME, zero-pad) accumulation into registers.
// Verbatim r4 conv_tile staging/compute: precomputed offsets, double-buffered
// LDS plane (one barrier per stage), PW=W+4 conflict-free float2 windows.
// plane must hold 2*CPS*(ROWS+2)*(W+4) floats.
// ---------------------------------------------------------------------------
template <int H, int W, int ROWS, int COG, int CPS, int PXT>
__device__ __forceinline__ void conv_core(
    const float* __restrict__ in, const float* __restrict__ wgt,
    int n, int rt, int cg_, float (&acc)[COG][PXT], float* plane)
{
    constexpr int NPIX = H * W;
    constexpr int PW   = W + 4;
    constexpr int CHSZ = (ROWS + 2) * PW;
    constexpr int LSZ  = CPS * CHSZ;
    constexpr int TXN  = W / PXT;
    constexpr int NS   = 48 / CPS;
    constexpr int LPT  = (LSZ + 255) / 256;
    static_assert(ROWS * TXN == 256, "block must be 256 threads");

    const int t   = threadIdx.x;
    const int co0 = cg_ * COG;
    const int tx  = t % TXN;
    const int ty  = t / TXN;
    const int x0  = tx * PXT;
    const int r0  = rt * ROWS;

#pragma unroll
    for (int co = 0; co < COG; ++co)
#pragma unroll
        for (int p = 0; p < PXT; ++p) acc[co][p] = 0.f;

    const float* inb = in + (size_t)n * 48 * NPIX;

    int off[LPT];
#pragma unroll
    for (int k = 0; k < LPT; ++k) {
        int i = t + k * 256;
        off[k] = -1;
        if (i < LSZ) {
            int ch  = i / CHSZ;
            int rem = i % CHSZ;
            int ly  = rem / PW, lx = rem % PW;
            int gy  = r0 + ly - 1, gx = lx - 1;
            if (gy >= 0 && gy < H && gx >= 0 && gx < W)
                off[k] = ch * NPIX + gy * W + gx;
        }
    }

    float pref[LPT];
#pragma unroll
    for (int k = 0; k < LPT; ++k)
        pref[k] = (off[k] >= 0) ? inb[off[k]] : 0.f;

    int buf = 0;
    for (int s = 0; s < NS; ++s) {
        float cur[LPT];
#pragma unroll
        for (int k = 0; k < LPT; ++k) cur[k] = pref[k];
        if (s + 1 < NS) {
            const float* nb = inb + (size_t)(s + 1) * CPS * NPIX;
#pragma unroll
            for (int k = 0; k < LPT; ++k)
                pref[k] = (off[k] >= 0) ? nb[off[k]] : 0.f;
        }
#pragma unroll
        for (int k = 0; k < LPT; ++k) {
            int i = t + k * 256;
            if (i < LSZ) plane[buf * LSZ + i] = cur[k];
        }
        __syncthreads();

#pragma unroll
        for (int c = 0; c < CPS; ++c) {
            const float* P = plane + buf * LSZ + c * CHSZ;
            float wv[COG][9];
#pragma unroll
            for (int co = 0; co < COG; ++co)
#pragma unroll
                for (int k = 0; k < 9; ++k)
                    wv[co][k] = wgt[((size_t)(co0 + co) * 48 + s * CPS + c) * 9 + k];
            float vr[3][PXT + 2];
            if constexpr (PXT == 2) {
#pragma unroll
                for (int r = 0; r < 3; ++r) {
                    float2 a = *(const float2*)(P + (ty + r) * PW + x0);
                    float2 b = *(const float2*)(P + (ty + r) * PW + x0 + 2);
                    vr[r][0] = a.x; vr[r][1] = a.y; vr[r][2] = b.x; vr[r][3] = b.y;
                }
            } else {
#pragma unroll
                for (int r = 0; r < 3; ++r)
#pragma unroll
                    for (int j = 0; j < PXT + 2; ++j)
                        vr[r][j] = P[(ty + r) * PW + x0 + j];
            }
#pragma unroll
            for (int co = 0; co < COG; ++co)
#pragma unroll
                for (int p = 0; p < PXT; ++p) {
                    float s0 = vr[0][p]     * wv[co][0] + vr[0][p + 1] * wv[co][1]
                             + vr[0][p + 2] * wv[co][2] + vr[1][p]     * wv[co][3]
                             + vr[1][p + 1] * wv[co][4] + vr[1][p + 2] * wv[co][5]
                             + vr[2][p]     * wv[co][6] + vr[2][p + 1] * wv[co][7]
                             + vr[2][p + 2] * wv[co][8];
                    acc[co][p] += s0;
                }
        }
        buf ^= 1;
    }
}

// ---------------------------------------------------------------------------
// One network phase: conv + bias, then
//   MODE 0: inorm, prelu, inorm, +res   (3 grid syncs)
//   MODE 1: inorm, prelu                (2 grid syncs)
//   MODE 2: raw conv + bias             (1 grid sync)
// Instance-norm stats via per-(pair,n,co,rt) partials in PST (deterministic,
// no atomics); conv outputs stay in registers the whole time.
// ---------------------------------------------------------------------------
template <int H, int W, int ROWS, int COG, int CPS, int PXT, int MODE, int NRT, int COUTT>
__device__ void phase_basic(cg::grid_group& g, bool active, int n, int rt, int cg_,
                            const float* __restrict__ in, const float* __restrict__ res,
                            const float* __restrict__ wgt, const float* __restrict__ bias,
                            const float* __restrict__ aptr, float* __restrict__ out,
                            float* __restrict__ PST, int pair, float* plane, float* red)
{
    constexpr int NPIX = H * W;
    constexpr int TXN  = W / PXT;
    constexpr float cntinv = 1.f / (float)NPIX;
    const int t  = threadIdx.x;
    const int tx = t % TXN, ty = t / TXN;
    const int x0 = tx * PXT, r0 = rt * ROWS;
    const int co0 = cg_ * COG;

    float acc[COG][PXT];

    if (active) {
        conv_core<H, W, ROWS, COG, CPS, PXT>(in, wgt, n, rt, cg_, acc, plane);
        float sv[2 * COG];
#pragma unroll
        for (int co = 0; co < COG; ++co) {
            const float bv = bias[co0 + co];
            float s = 0.f, s2 = 0.f;
#pragma unroll
            for (int p = 0; p < PXT; ++p) {
                acc[co][p] += bv;
                s += acc[co][p]; s2 += acc[co][p] * acc[co][p];
            }
            sv[2 * co] = s; sv[2 * co + 1] = s2;
        }
        if (MODE != 2) {
            block_reduce_vec<2 * COG>(sv, red);
            if (t < 2 * COG)
                PST[(((size_t)pair * 4 + n) * 48 + co0 + (t >> 1)) * 16 + rt * 2 + (t & 1)] = red[t];
        }
    }

    if (MODE != 2) {
        g.sync();
        if (active) {
            if (t < 2 * COG) {
                size_t base = (((size_t)pair * 4 + n) * 48 + co0 + (t >> 1)) * 16 + (t & 1);
                float tot = 0.f;
#pragma unroll
                for (int r = 0; r < NRT; ++r) tot += PST[base + r * 2];
                red[t] = tot;
            }
            __syncthreads();
            const float a = aptr[0];
            float mm[COG], rr[COG];
#pragma unroll
            for (int co = 0; co < COG; ++co) {
                float m = red[2 * co] * cntinv;
                float v = red[2 * co + 1] * cntinv - m * m;
                mm[co] = m; rr[co] = rsqrtf(v + 1e-5f);
            }
            float sv[2 * COG];
#pragma unroll
            for (int co = 0; co < COG; ++co) {
                float s = 0.f, s2 = 0.f;
#pragma unroll
                for (int p = 0; p < PXT; ++p) {
                    float z = (acc[co][p] - mm[co]) * rr[co];
                    z = z >= 0.f ? z : a * z;
                    acc[co][p] = z;
                    s += z; s2 += z * z;
                }
                sv[2 * co] = s; sv[2 * co + 1] = s2;
            }
            if (MODE == 0) {
                block_reduce_vec<2 * COG>(sv, red);
                if (t < 2 * COG)
                    PST[(((size_t)(pair + 1) * 4 + n) * 48 + co0 + (t >> 1)) * 16 + rt * 2 + (t & 1)] = red[t];
            }
        }
        if (MODE == 0) {
            g.sync();
            if (active) {
                if (t < 2 * COG) {
                    size_t base = (((size_t)(pair + 1) * 4 + n) * 48 + co0 + (t >> 1)) * 16 + (t & 1);
                    float tot = 0.f;
#pragma unroll
                    for (int r = 0; r < NRT; ++r) tot += PST[base + r * 2];
                    red[t] = tot;
                }
                __syncthreads();
#pragma unroll
                for (int co = 0; co < COG; ++co) {
                    float m = red[2 * co] * cntinv;
                    float v = red[2 * co + 1] * cntinv - m * m;
                    float rs = rsqrtf(v + 1e-5f);
                    const float* rp = res + ((size_t)n * 48 + co0 + co) * NPIX + (r0 + ty) * W + x0;
#pragma unroll
                    for (int p = 0; p < PXT; ++p)
                        acc[co][p] = (acc[co][p] - m) * rs + rp[p];
                }
            }
        }
    }

    if (active) {
#pragma unroll
        for (int co = 0; co < COG; ++co) {
            float* op = out + (((size_t)n * COUTT + co0 + co) * H + r0 + ty) * W + x0;
            if (PXT == 2) {
                *(float2*)op = make_float2(acc[co][0], acc[co][1]);
            } else {
#pragma unroll
                for (int p = 0; p < PXT; ++p) op[p] = acc[co][p];
            }
        }
    }
    g.sync();
}

// ---------------------------------------------------------------------------
// The whole mid-network in ONE cooperative launch: downsample, 3 basic
// blocks @64x64, maxpool, 3 basic blocks @32x32, head conv+inorm+prelu,
// 9-cout kernel-prediction conv. Grid 512 x 256 (2 blocks/CU co-resident).
// ---------------------------------------------------------------------------
__global__ __launch_bounds__(256, 2) void net_mega(
    const float* __restrict__ x_,
    const float* __restrict__ w1, const float* __restrict__ b1, const float* __restrict__ a1,
    const float* __restrict__ w2, const float* __restrict__ b2, const float* __restrict__ a2,
    const float* __restrict__ kw1, const float* __restrict__ kb1, const float* __restrict__ ka,
    const float* __restrict__ kw2, const float* __restrict__ kb2,
    float* A, float* B, float* C, float* D, float* SK, float* PST)
{
    cg::grid_group g = cg::this_grid();
    __shared__ __align__(16) float splane[2 * 1440];   // max of 64²(CPS=2) / 32²(CPS=4)
    __shared__ float red[34];
    const int b = blockIdx.x;
    const int t = threadIdx.x;
    const int W1 = 48 * 48 * 9;

    // ---- phase 0: downsample x_ (::4,::4) -> A ----
    for (int idx = b * 256 + t; idx < 786432; idx += 512 * 256) {
        int j = idx & 63, i = (idx >> 6) & 63, nc = idx >> 12;
        A[idx] = x_[((size_t)nc * 256 + i * 4) * 256 + j * 4];
    }
    g.sync();

    // ---- 3 basic blocks @64x64 : 16cg x 8rt x 4n = 512 blocks, all active ----
    {
        const int n = b & 3, rt = (b >> 2) & 7, cg_ = b >> 5;
        float* io[4] = { A, B, A, B };
#pragma unroll 1
        for (int i = 0; i < 3; ++i)
            phase_basic<64, 64, 8, 3, 2, 2, 0, 8, 48>(g, true, n, rt, cg_,
                io[i], io[i], w1 + i * W1, b1 + i * 48, a1 + i,
                io[i + 1], PST, 2 * i, splane, red);
    }

    // ---- maxpool B(64²) -> C(32²) ----
    for (int idx = b * 256 + t; idx < 196608; idx += 512 * 256) {
        int j = idx & 31, i = (idx >> 5) & 31, nc = idx >> 10;
        const float* p = B + ((size_t)nc * 64 + i * 2) * 64 + j * 2;
        C[idx] = fmaxf(fmaxf(p[0], p[1]), fmaxf(p[64], p[65]));
    }
    g.sync();

    // ---- 3 basic blocks @32x32 : 24cg x 4rt x 4n = 384 active ----
    {
        const bool act = b < 384;
        const int n = b & 3, rt = (b >> 2) & 3, cg_ = b >> 4;
        float* io[4] = { C, D, C, D };
#pragma unroll 1
        for (int i = 0; i < 3; ++i)
            phase_basic<32, 32, 8, 2, 4, 1, 0, 4, 48>(g, act, n, rt, cg_,
                io[i], io[i], w2 + i * W1, b2 + i * 48, a2 + i,
                io[i + 1], PST, 6 + 2 * i, splane, red);

        // head: conv48 + inorm + prelu : D -> C
        phase_basic<32, 32, 8, 2, 4, 1, 1, 4, 48>(g, act, n, rt, cg_,
            D, nullptr, kw1, kb1, ka, C, PST, 12, splane, red);
    }

    // ---- kernel-prediction conv (9 couts) : C -> SK ----
    {
        const bool act = b < 48;
        const int n = b & 3, rt = (b >> 2) & 3, cg_ = b >> 4;
        phase_basic<32, 32, 8, 3, 4, 1, 2, 4, 9>(g, act, n, rt, cg_,
            C, nullptr, kw2, kb2, nullptr, SK, PST, 0, splane, red);
    }
}

// ---------------------------------------------------------------------------
// Fused: bilinear 8x upsample of skernel (4,9,32,32), per-pixel softmax,
// 3x3 reflect-padded apply to x. Grid (16, 256). Halo via cross-lane
// shuffle; kvs p-major for conflict-free LDS; loads hoisted.
// ---------------------------------------------------------------------------
__global__ __launch_bounds__(256) void apply_fused(const float* __restrict__ x,
                                                   const float* __restrict__ sk,
                                                   float* __restrict__ out)
{
    __shared__ float skr[9][2][32];
    __shared__ float kvs[9][256];    // p-major
    const int bx = blockIdx.x;
    const int n  = bx >> 2;
    const int cg = bx & 3;
    const int h  = blockIdx.y;
    const int t  = threadIdx.x;

    float fs = (float)h * 31.0f / 255.0f;
    int r0 = (int)fs;
    float fh = fs - (float)r0;
    int r1 = min(r0 + 1, 31);

    for (int i = t; i < 576; i += 256) {
        int p = i >> 6, rsel = (i >> 5) & 1, c = i & 31;
        int rr = rsel ? r1 : r0;
        skr[p][rsel][c] = sk[((n * 9 + p) * 32 + rr) * 32 + c];
    }
    __syncthreads();

    {
        float fcs = (float)t * 31.0f / 255.0f;
        int c0 = (int)fcs;
        float fx = fcs - (float)c0;
        int c1 = min(c0 + 1, 31);
        float kv[9];
        float mx = -1e30f;
#pragma unroll
        for (int p = 0; p < 9; ++p) {
            float v0 = skr[p][0][c0] * (1.f - fx) + skr[p][0][c1] * fx;
            float v1 = skr[p][1][c0] * (1.f - fx) + skr[p][1][c1] * fx;
            float v  = v0 * (1.f - fh) + v1 * fh;
            kv[p] = v;
            mx = fmaxf(mx, v);
        }
        float ss = 0.f;
#pragma unroll
        for (int p = 0; p < 9; ++p) { kv[p] = __expf(kv[p] - mx); ss += kv[p]; }
        float inv = 1.f / ss;
#pragma unroll
        for (int p = 0; p < 9; ++p) kvs[p][t] = kv[p] * inv;
    }
    __syncthreads();

    const int wq = t & 63;
    const int cl = t >> 6;
    const int w4 = wq * 4;

    float kv[4][9];
#pragma unroll
    for (int p = 0; p < 9; ++p) {
        float4 v = *(const float4*)&kvs[p][w4];
        kv[0][p] = v.x; kv[1][p] = v.y; kv[2][p] = v.z; kv[3][p] = v.w;
    }

    const int hm  = (h == 0) ? 1 : h - 1;
    const int hp  = (h == 255) ? 254 : h + 1;

    const int c0ch = cg * 12 + cl * 3;
    const float* xb = x + ((size_t)n * HIDC + c0ch) * 65536;
    float* ob = out + ((size_t)n * HIDC + c0ch) * 65536;

    float4 F[3][3];
#pragma unroll
    for (int c = 0; c < 3; ++c) {
        const float* xp = xb + (size_t)c * 65536;
        F[c][0] = *(const float4*)(xp + hm * 256 + w4);
        F[c][1] = *(const float4*)(xp + h  * 256 + w4);
        F[c][2] = *(const float4*)(xp + hp * 256 + w4);
    }

#pragma unroll
    for (int c = 0; c < 3; ++c) {
        float4 fm = F[c][0];
        float4 fc = F[c][1];
        float4 fp = F[c][2];
        float lm = __shfl_up(fm.w, 1);   if (wq == 0)  lm = fm.y;
        float lc = __shfl_up(fc.w, 1);   if (wq == 0)  lc = fc.y;
        float lp = __shfl_up(fp.w, 1);   if (wq == 0)  lp = fp.y;
        float rmr = __shfl_down(fm.x, 1); if (wq == 63) rmr = fm.z;
        float rcr = __shfl_down(fc.x, 1); if (wq == 63) rcr = fc.z;
        float rpr = __shfl_down(fp.x, 1); if (wq == 63) rpr = fp.z;
        float vm[6] = { lm, fm.x, fm.y, fm.z, fm.w, rmr };
        float vc[6] = { lc, fc.x, fc.y, fc.z, fc.w, rcr };
        float vp[6] = { lp, fp.x, fp.y, fp.z, fp.w, rpr };
        float4 o;
        float* op = &o.x;
#pragma unroll
        for (int j = 0; j < 4; ++j) {
            op[j] = kv[j][0] * vm[j] + kv[j][1] * vm[j + 1] + kv[j][2] * vm[j + 2]
                  + kv[j][3] * vc[j] + kv[j][4] * vc[j + 1] + kv[j][5] * vc[j + 2]
                  + kv[j][6] * vp[j] + kv[j][7] * vp[j + 1] + kv[j][8] * vp[j + 2];
        }
        *(float4*)(ob + (size_t)c * 65536 + h * 256 + w4) = o;
    }
}

extern "C" void kernel_launch(void* const* d_in, const int* in_sizes, int n_in,
                              void* d_out, int out_size, void* d_ws, size_t ws_size,
                              hipStream_t stream)
{
    (void)in_sizes; (void)n_in; (void)out_size; (void)ws_size;
    const float* x       = (const float*)d_in[0];
    const float* x_      = (const float*)d_in[1];
    const float* pre1_w  = (const float*)d_in[2];
    const float* pre1_b  = (const float*)d_in[3];
    const float* pre1_a  = (const float*)d_in[4];
    const float* pre2_w  = (const float*)d_in[5];
    const float* pre2_b  = (const float*)d_in[6];
    const float* pre2_a  = (const float*)d_in[7];
    const float* prek_w1 = (const float*)d_in[8];
    const float* prek_b1 = (const float*)d_in[9];
    const float* prek_a  = (const float*)d_in[10];
    const float* prek_w2 = (const float*)d_in[11];
    const float* prek_b2 = (const float*)d_in[12];
    float* out = (float*)d_out;

    float* A   = (float*)d_ws;          // (4,48,64,64) = 786432
    float* B   = A + 786432;            // (4,48,64,64)
    float* C   = B + 786432;            // (4,48,32,32) = 196608
    float* D   = C + 196608;            // (4,48,32,32)
    float* SK  = D + 196608;            // (4,9,32,32)  = 36864
    float* PST = SK + 36864;            // 13 pairs x 4n x 48co x 8rt x 2 = 39936

    void* kargs[] = {
        (void*)&x_,
        (void*)&pre1_w, (void*)&pre1_b, (void*)&pre1_a,
        (void*)&pre2_w, (void*)&pre2_b, (void*)&pre2_a,
        (void*)&prek_w1, (void*)&prek_b1, (void*)&prek_a,
        (void*)&prek_w2, (void*)&prek_b2,
        (void*)&A, (void*)&B, (void*)&C, (void*)&D, (void*)&SK, (void*)&PST
    };
    hipLaunchCooperativeKernel((const void*)net_mega, dim3(512), dim3(256),
                               kargs, 0, stream);

    apply_fused<<<dim3(16, 256), 256, 0, stream>>>(x, SK, out);
}

// Round 6
// 310.599 us; speedup vs baseline: 5.0001x; 5.0001x over previous
//
#include <hip/hip_runtime.h>
#include <cmath>

#define HIDC 48

// ---------------------------------------------------------------------------
// block-wide mean/var over NPIX values spread across 16 waves (1024 threads).
// ---------------------------------------------------------------------------
__device__ __forceinline__ void block_meanvar1024(float s, float s2, float* red,
                                                  float cntinv, float& m, float& v)
{
#pragma unroll
    for (int off = 32; off > 0; off >>= 1) {
        s  += __shfl_down(s, off);
        s2 += __shfl_down(s2, off);
    }
    int wid  = threadIdx.x >> 6;   // 0..15
    int lane = threadIdx.x & 63;
    if (lane == 0) { red[wid] = s; red[16 + wid] = s2; }
    __syncthreads();
    if (threadIdx.x == 0) {
        float ts = 0.f, ts2 = 0.f;
#pragma unroll
        for (int i = 0; i < 16; ++i) { ts += red[i]; ts2 += red[16 + i]; }
        red[32] = ts; red[33] = ts2;
    }
    __syncthreads();
    float mean = red[32] * cntinv;
    m = mean;
    v = red[33] * cntinv - mean * mean;
    __syncthreads();
}

// ---------------------------------------------------------------------------
// Split-K partial conv3x3(SAME, zero-pad), NO bias (bias cancels in the
// following instance-norm; SK-conv bias is added in apply_fused).
// Each block computes COG couts x ROWS rows x W cols over NCH=24 input
// channels (half = blockIdx.z&1, n = blockIdx.z>>1) and writes a partial
// conv to out + half*4*COUT*NPIX. The following norm sums the partials.
// Why split: grid doubles (2048 blocks @64², 8 blocks/CU, 16 waves/CU vs
// r4's 2-blocks/CU grid cap at 25% occupancy) — conv was latency-bound.
//  - 128-thread blocks (ROWS=4): cheaper barriers, finer scheduling.
//  - Stage addresses precomputed ONCE into off[] (-1 = zero pad).
//  - PW = W+4: conflict-free float2/scalar LDS windows (2 lanes/bank max).
//  - Double-buffered LDS, ONE barrier per stage (stage s+1 writes the
//    buffer read at s-1 => safe).
//  - r3 lesson: never stage strided-by-4 global reads (cacheline blowup).
// ---------------------------------------------------------------------------
template <int H, int W, int ROWS, int COG, int CPS, int PXT, int NCH>
__global__ __launch_bounds__(ROWS*(W/PXT)) void conv_tile(
    const float* __restrict__ in,    // (N, 48, H, W)
    const float* __restrict__ wgt,   // (COUT, 48, 3, 3)
    float* __restrict__ out)         // (2, N, COUT, H, W) partials
{
    constexpr int THREADS = ROWS * (W / PXT);
    constexpr int NPIX = H * W;
    constexpr int PW   = W + 4;
    constexpr int CHSZ = (ROWS + 2) * PW;
    constexpr int LSZ  = CPS * CHSZ;
    constexpr int TXN  = W / PXT;          // threads per row
    constexpr int NS   = NCH / CPS;
    constexpr int LPT  = (LSZ + THREADS - 1) / THREADS;

    __shared__ float plane[2][LSZ];

    const int t    = threadIdx.x;
    const int cg   = blockIdx.x;
    const int rt   = blockIdx.y;
    const int z    = blockIdx.z;
    const int half = z & 1;
    const int n    = z >> 1;
    const int COUT = gridDim.x * COG;
    const int co0  = cg * COG;
    const int cin0 = half * NCH;
    const int tx   = t % TXN;
    const int ty   = t / TXN;              // row within tile
    const int x0   = tx * PXT;
    const int r0   = rt * ROWS;
    const size_t OSTRIDE = (size_t)4 * COUT * NPIX;

    float acc[COG][PXT];
#pragma unroll
    for (int co = 0; co < COG; ++co)
#pragma unroll
        for (int p = 0; p < PXT; ++p) acc[co][p] = 0.f;

    const float* inb = in + ((size_t)n * 48 + cin0) * NPIX;

    // precompute staging offsets (loop-invariant across stages)
    int off[LPT];
#pragma unroll
    for (int k = 0; k < LPT; ++k) {
        int i = t + k * THREADS;
        off[k] = -1;
        if (i < LSZ) {
            int ch  = i / CHSZ;
            int rem = i % CHSZ;
            int ly  = rem / PW, lx = rem % PW;
            int gy  = r0 + ly - 1, gx = lx - 1;
            if (gy >= 0 && gy < H && gx >= 0 && gx < W)
                off[k] = ch * NPIX + gy * W + gx;
        }
    }

    // prefetch stage 0
    float pref[LPT];
#pragma unroll
    for (int k = 0; k < LPT; ++k)
        pref[k] = (off[k] >= 0) ? inb[off[k]] : 0.f;

    int buf = 0;
    for (int s = 0; s < NS; ++s) {
        float cur[LPT];
#pragma unroll
        for (int k = 0; k < LPT; ++k) cur[k] = pref[k];
        if (s + 1 < NS) {
            const float* nb = inb + (size_t)(s + 1) * CPS * NPIX;
#pragma unroll
            for (int k = 0; k < LPT; ++k)
                pref[k] = (off[k] >= 0) ? nb[off[k]] : 0.f;
        }
#pragma unroll
        for (int k = 0; k < LPT; ++k) {
            int i = t + k * THREADS;
            if (i < LSZ) plane[buf][i] = cur[k];
        }
        __syncthreads();

#pragma unroll
        for (int c = 0; c < CPS; ++c) {
            const float* P = &plane[buf][c * CHSZ];
            float wv[COG][9];
#pragma unroll
            for (int co = 0; co < COG; ++co)
#pragma unroll
                for (int k = 0; k < 9; ++k)
                    wv[co][k] = wgt[((size_t)(co0 + co) * 48 + cin0 + s * CPS + c) * 9 + k];
            // window rows ty..ty+2, cols x0..x0+PXT+1
            float vr[3][PXT + 2];
            if constexpr (PXT == 2) {
#pragma unroll
                for (int r = 0; r < 3; ++r) {
                    float2 a = *(const float2*)(P + (ty + r) * PW + x0);
                    float2 b = *(const float2*)(P + (ty + r) * PW + x0 + 2);
                    vr[r][0] = a.x; vr[r][1] = a.y; vr[r][2] = b.x; vr[r][3] = b.y;
                }
            } else {
#pragma unroll
                for (int r = 0; r < 3; ++r)
#pragma unroll
                    for (int j = 0; j < PXT + 2; ++j)
                        vr[r][j] = P[(ty + r) * PW + x0 + j];
            }
#pragma unroll
            for (int co = 0; co < COG; ++co)
#pragma unroll
                for (int p = 0; p < PXT; ++p) {
                    float s0 = vr[0][p]     * wv[co][0] + vr[0][p + 1] * wv[co][1]
                             + vr[0][p + 2] * wv[co][2] + vr[1][p]     * wv[co][3]
                             + vr[1][p + 1] * wv[co][4] + vr[1][p + 2] * wv[co][5]
                             + vr[2][p]     * wv[co][6] + vr[2][p + 1] * wv[co][7]
                             + vr[2][p + 2] * wv[co][8];
                    acc[co][p] += s0;
                }
        }
        buf ^= 1;
    }

#pragma unroll
    for (int co = 0; co < COG; ++co) {
        float* op = out + half * OSTRIDE
                  + (((size_t)n * COUT + co0 + co) * H + r0 + ty) * W + x0;
        if (PXT == 2) {
            *(float2*)op = make_float2(acc[co][0], acc[co][1]);
        } else {
#pragma unroll
            for (int p = 0; p < PXT; ++p) op[p] = acc[co][p];
        }
    }
}

// ---------------------------------------------------------------------------
// Per-plane epilogue on the SUM of two split-K partials:
//   MODE 0: inorm, prelu, inorm, +res    MODE 1: inorm, prelu
//   POOL 1: (MODE 0 only, NPIX=4096) thread owns a 2x2 quad; after the
//           residual add, pools max-2x2 in-register and writes the 32x32
//           plane (fuses maxpool2, saves a dispatch + round-trip).
// ---------------------------------------------------------------------------
template <int NPIX, int MODE, int POOL>
__global__ __launch_bounds__(1024) void norm_block(
    const float* __restrict__ c0,
    const float* __restrict__ c1,
    const float* __restrict__ res,
    const float* __restrict__ aptr,
    float* __restrict__ out)
{
    constexpr int TY = NPIX / 1024;
    __shared__ float red[34];
    const int t  = threadIdx.x;
    const int co = blockIdx.x;
    const int n  = blockIdx.y;
    const size_t base = ((size_t)n * 48 + co) * NPIX;
    constexpr float cntinv = 1.f / (float)NPIX;

    float acc[TY];
    size_t q = 0;
    if constexpr (POOL) {
        const int i = t >> 5, j = t & 31;       // quad (2i,2j)
        q = base + (size_t)i * 128 + j * 2;
        float2 a0 = *(const float2*)(c0 + q);
        float2 a1 = *(const float2*)(c0 + q + 64);
        float2 b0 = *(const float2*)(c1 + q);
        float2 b1 = *(const float2*)(c1 + q + 64);
        acc[0] = a0.x + b0.x; acc[1] = a0.y + b0.y;
        acc[2] = a1.x + b1.x; acc[3] = a1.y + b1.y;
    } else {
#pragma unroll
        for (int r = 0; r < TY; ++r)
            acc[r] = c0[base + t + r * 1024] + c1[base + t + r * 1024];
    }

    {
        float s = 0.f, s2 = 0.f;
#pragma unroll
        for (int r = 0; r < TY; ++r) { s += acc[r]; s2 += acc[r] * acc[r]; }
        float m, v;
        block_meanvar1024(s, s2, red, cntinv, m, v);
        float rr = rsqrtf(v + 1e-5f);
#pragma unroll
        for (int r = 0; r < TY; ++r) acc[r] = (acc[r] - m) * rr;
    }

    const float a = aptr[0];
#pragma unroll
    for (int r = 0; r < TY; ++r) acc[r] = acc[r] >= 0.f ? acc[r] : a * acc[r];

    if (MODE == 0) {
        float s = 0.f, s2 = 0.f;
#pragma unroll
        for (int r = 0; r < TY; ++r) { s += acc[r]; s2 += acc[r] * acc[r]; }
        float m, v;
        block_meanvar1024(s, s2, red, cntinv, m, v);
        float rr = rsqrtf(v + 1e-5f);
        if constexpr (POOL) {
            float2 r0v = *(const float2*)(res + q);
            float2 r1v = *(const float2*)(res + q + 64);
            acc[0] = (acc[0] - m) * rr + r0v.x;
            acc[1] = (acc[1] - m) * rr + r0v.y;
            acc[2] = (acc[2] - m) * rr + r1v.x;
            acc[3] = (acc[3] - m) * rr + r1v.y;
        } else {
#pragma unroll
            for (int r = 0; r < TY; ++r)
                acc[r] = (acc[r] - m) * rr + res[base + t + r * 1024];
        }
    }

    if constexpr (POOL) {
        out[(((size_t)n * 48 + co) << 10) + t] =
            fmaxf(fmaxf(acc[0], acc[1]), fmaxf(acc[2], acc[3]));
    } else {
#pragma unroll
        for (int r = 0; r < TY; ++r) out[base + t + r * 1024] = acc[r];
    }
}

// ---------------------------------------------------------------------------
__global__ __launch_bounds__(256) void downsample4(const float* __restrict__ xin,
                                                   float* __restrict__ o)
{
    int idx = blockIdx.x * 256 + threadIdx.x;        // 786432
    int j = idx & 63;
    int i = (idx >> 6) & 63;
    int nc = idx >> 12;
    o[idx] = xin[((size_t)nc * 256 + i * 4) * 256 + j * 4];
}

// ---------------------------------------------------------------------------
// Fused: bilinear 8x upsample of skernel partials (sk0+sk1+bias), per-pixel
// softmax, 3x3 reflect-padded apply to x. Grid (16, 256). Halo via
// cross-lane shuffle; kvs p-major conflict-free; loads hoisted.
// ---------------------------------------------------------------------------
__global__ __launch_bounds__(256) void apply_fused(const float* __restrict__ x,
                                                   const float* __restrict__ sk0,
                                                   const float* __restrict__ sk1,
                                                   const float* __restrict__ kb2,
                                                   float* __restrict__ out)
{
    __shared__ float skr[9][2][32];
    __shared__ float kvs[9][256];    // p-major
    const int bx = blockIdx.x;
    const int n  = bx >> 2;
    const int cg = bx & 3;
    const int h  = blockIdx.y;
    const int t  = threadIdx.x;

    float fs = (float)h * 31.0f / 255.0f;
    int r0 = (int)fs;
    float fh = fs - (float)r0;
    int r1 = min(r0 + 1, 31);

    for (int i = t; i < 576; i += 256) {
        int p = i >> 6, rsel = (i >> 5) & 1, c = i & 31;
        int rr = rsel ? r1 : r0;
        int idx = ((n * 9 + p) * 32 + rr) * 32 + c;
        skr[p][rsel][c] = sk0[idx] + sk1[idx] + kb2[p];
    }
    __syncthreads();

    {
        float fcs = (float)t * 31.0f / 255.0f;
        int c0 = (int)fcs;
        float fx = fcs - (float)c0;
        int c1 = min(c0 + 1, 31);
        float kv[9];
        float mx = -1e30f;
#pragma unroll
        for (int p = 0; p < 9; ++p) {
            float v0 = skr[p][0][c0] * (1.f - fx) + skr[p][0][c1] * fx;
            float v1 = skr[p][1][c0] * (1.f - fx) + skr[p][1][c1] * fx;
            float v  = v0 * (1.f - fh) + v1 * fh;
            kv[p] = v;
            mx = fmaxf(mx, v);
        }
        float ss = 0.f;
#pragma unroll
        for (int p = 0; p < 9; ++p) { kv[p] = __expf(kv[p] - mx); ss += kv[p]; }
        float inv = 1.f / ss;
#pragma unroll
        for (int p = 0; p < 9; ++p) kvs[p][t] = kv[p] * inv;
    }
    __syncthreads();

    const int wq = t & 63;           // lane within wave == pixel quad
    const int cl = t >> 6;           // wave id == channel subgroup
    const int w4 = wq * 4;

    float kv[4][9];
#pragma unroll
    for (int p = 0; p < 9; ++p) {
        float4 v = *(const float4*)&kvs[p][w4];
        kv[0][p] = v.x; kv[1][p] = v.y; kv[2][p] = v.z; kv[3][p] = v.w;
    }

    const int hm  = (h == 0) ? 1 : h - 1;
    const int hp  = (h == 255) ? 254 : h + 1;

    const int c0ch = cg * 12 + cl * 3;
    const float* xb = x + ((size_t)n * HIDC + c0ch) * 65536;
    float* ob = out + ((size_t)n * HIDC + c0ch) * 65536;

    float4 F[3][3];
#pragma unroll
    for (int c = 0; c < 3; ++c) {
        const float* xp = xb + (size_t)c * 65536;
        F[c][0] = *(const float4*)(xp + hm * 256 + w4);
        F[c][1] = *(const float4*)(xp + h  * 256 + w4);
        F[c][2] = *(const float4*)(xp + hp * 256 + w4);
    }

#pragma unroll
    for (int c = 0; c < 3; ++c) {
        float4 fm = F[c][0];
        float4 fc = F[c][1];
        float4 fp = F[c][2];
        float lm = __shfl_up(fm.w, 1);   if (wq == 0)  lm = fm.y;
        float lc = __shfl_up(fc.w, 1);   if (wq == 0)  lc = fc.y;
        float lp = __shfl_up(fp.w, 1);   if (wq == 0)  lp = fp.y;
        float rmr = __shfl_down(fm.x, 1); if (wq == 63) rmr = fm.z;
        float rcr = __shfl_down(fc.x, 1); if (wq == 63) rcr = fc.z;
        float rpr = __shfl_down(fp.x, 1); if (wq == 63) rpr = fp.z;
        float vm[6] = { lm, fm.x, fm.y, fm.z, fm.w, rmr };
        float vc[6] = { lc, fc.x, fc.y, fc.z, fc.w, rcr };
        float vp[6] = { lp, fp.x, fp.y, fp.z, fp.w, rpr };
        float4 o;
        float* op = &o.x;
#pragma unroll
        for (int j = 0; j < 4; ++j) {
            op[j] = kv[j][0] * vm[j] + kv[j][1] * vm[j + 1] + kv[j][2] * vm[j + 2]
                  + kv[j][3] * vc[j] + kv[j][4] * vc[j + 1] + kv[j][5] * vc[j + 2]
                  + kv[j][6] * vp[j] + kv[j][7] * vp[j + 1] + kv[j][8] * vp[j + 2];
        }
        *(float4*)(ob + (size_t)c * 65536 + h * 256 + w4) = o;
    }
}

extern "C" void kernel_launch(void* const* d_in, const int* in_sizes, int n_in,
                              void* d_out, int out_size, void* d_ws, size_t ws_size,
                              hipStream_t stream)
{
    (void)in_sizes; (void)n_in; (void)out_size; (void)ws_size;
    const float* x       = (const float*)d_in[0];
    const float* x_      = (const float*)d_in[1];
    const float* pre1_w  = (const float*)d_in[2];
    const float* pre1_a  = (const float*)d_in[4];
    const float* pre2_w  = (const float*)d_in[5];
    const float* pre2_a  = (const float*)d_in[7];
    const float* prek_w1 = (const float*)d_in[8];
    const float* prek_a  = (const float*)d_in[10];
    const float* prek_w2 = (const float*)d_in[11];
    const float* prek_b2 = (const float*)d_in[12];
    float* out = (float*)d_out;

    float* A   = (float*)d_ws;          // (4,48,64,64) = 786432
    float* B   = A + 786432;            // (4,48,64,64)
    float* R0  = B + 786432;            // partial conv half0 (<= 786432)
    float* R1  = R0 + 786432;           // partial conv half1
    float* C   = R1 + 786432;           // (4,48,32,32) = 196608
    float* D   = C + 196608;            // (4,48,32,32)
    float* SK0 = D + 196608;            // (4,9,32,32) = 36864
    float* SK1 = SK0 + 36864;

    const int W1 = 48 * 48 * 9;

    downsample4<<<3072, 256, 0, stream>>>(x_, A);

    // ---- 3 basic blocks @64x64: split-K conv (2048 blocks x 128thd) ----
    conv_tile<64, 64, 4, 3, 2, 2, 24><<<dim3(16, 16, 8), 128, 0, stream>>>(A, pre1_w, R0);
    norm_block<4096, 0, 0><<<dim3(48, 4), 1024, 0, stream>>>(R0, R1, A, pre1_a, B);
    conv_tile<64, 64, 4, 3, 2, 2, 24><<<dim3(16, 16, 8), 128, 0, stream>>>(B, pre1_w + W1, R0);
    norm_block<4096, 0, 0><<<dim3(48, 4), 1024, 0, stream>>>(R0, R1, B, pre1_a + 1, A);
    conv_tile<64, 64, 4, 3, 2, 2, 24><<<dim3(16, 16, 8), 128, 0, stream>>>(A, pre1_w + 2 * W1, R0);
    // third norm fuses maxpool2 -> writes pooled 32x32 planes into C
    norm_block<4096, 0, 1><<<dim3(48, 4), 1024, 0, stream>>>(R0, R1, A, pre1_a + 2, C);

    // ---- 3 basic blocks @32x32: split-K conv (1536 blocks x 128thd) ----
    conv_tile<32, 32, 4, 2, 4, 1, 24><<<dim3(24, 8, 8), 128, 0, stream>>>(C, pre2_w, R0);
    norm_block<1024, 0, 0><<<dim3(48, 4), 1024, 0, stream>>>(R0, R0 + 196608, C, pre2_a, D);
    conv_tile<32, 32, 4, 2, 4, 1, 24><<<dim3(24, 8, 8), 128, 0, stream>>>(D, pre2_w + W1, R0);
    norm_block<1024, 0, 0><<<dim3(48, 4), 1024, 0, stream>>>(R0, R0 + 196608, D, pre2_a + 1, C);
    conv_tile<32, 32, 4, 2, 4, 1, 24><<<dim3(24, 8, 8), 128, 0, stream>>>(C, pre2_w + 2 * W1, R0);
    norm_block<1024, 0, 0><<<dim3(48, 4), 1024, 0, stream>>>(R0, R0 + 196608, C, pre2_a + 2, D);

    // ---- kernel-prediction heads ----
    conv_tile<32, 32, 4, 2, 4, 1, 24><<<dim3(24, 8, 8), 128, 0, stream>>>(D, prek_w1, R0);
    norm_block<1024, 1, 0><<<dim3(48, 4), 1024, 0, stream>>>(R0, R0 + 196608, nullptr, prek_a, C);
    conv_tile<32, 32, 4, 3, 4, 1, 24><<<dim3(3, 8, 8), 128, 0, stream>>>(C, prek_w2, SK0);

    apply_fused<<<dim3(16, 256), 256, 0, stream>>>(x, SK0, SK1, prek_b2, out);
}